// Round 16
// baseline (29.756 us; speedup 1.0000x reference)
//
#include <hip/hip_runtime.h>
#include <hip/hip_bf16.h>

#define B_  16
#define C_  64
#define HW  4096   // 64*64
#define KP  1024   // pooled positions (32*32)
#define LOG2E 1.44269504088896f

typedef short short8 __attribute__((ext_vector_type(8)));
typedef float floatx16 __attribute__((ext_vector_type(16)));

union Frag { uint4 u; short8 s; };

__device__ __forceinline__ unsigned cvt_pk_bf16(float lo, float hi) {
    unsigned r;
    asm("v_cvt_pk_bf16_f32 %0, %1, %2" : "=v"(r) : "v"(lo), "v"(hi));
    return r;
}
#define PLSWAP(a, b) asm("v_permlane32_swap_b32 %0, %1" : "+v"(a), "+v"(b))

// Build two PV A-operand fragments (K=16 each) from 16 lane-local P values.
__device__ __forceinline__ void build_pfrags(const float* p, Frag& f0, Frag& f1) {
    unsigned u0 = cvt_pk_bf16(p[0], p[1]);
    unsigned u1 = cvt_pk_bf16(p[2], p[3]);
    unsigned u2 = cvt_pk_bf16(p[4], p[5]);
    unsigned u3 = cvt_pk_bf16(p[6], p[7]);
    PLSWAP(u0, u2);
    PLSWAP(u1, u3);
    f0.u.x = u0; f0.u.y = u1; f0.u.z = u2; f0.u.w = u3;
    unsigned v0 = cvt_pk_bf16(p[8],  p[9]);
    unsigned v1 = cvt_pk_bf16(p[10], p[11]);
    unsigned v2 = cvt_pk_bf16(p[12], p[13]);
    unsigned v3 = cvt_pk_bf16(p[14], p[15]);
    PLSWAP(v0, v2);
    PLSWAP(v1, v3);
    f1.u.x = v0; f1.u.y = v1; f1.u.z = v2; f1.u.w = v3;
}

// ---- conv kernel LDS (bytes) ----
#define XS_ROW   528          // 132 floats
#define CV_ROW2  532          // 133 floats
#define CV_HALF  25536        // 48*532
#define CLDS_SZ  51072

// ---------------------------------------------------------------------------
// Kernel A (v6, ~5us): MFMA 1x1 conv (48 oc) + 2x2 pool. Unchanged:
// compact theta/phi; g written in MFMA fragment order.
// ---------------------------------------------------------------------------
__global__ __launch_bounds__(256) void convpool_kernel(
    const float* __restrict__ x,
    const float* __restrict__ w_theta,
    const float* __restrict__ w_phi,
    const float* __restrict__ w_g,
    __hip_bfloat16* __restrict__ theta16,
    __hip_bfloat16* __restrict__ phi16,
    __hip_bfloat16* __restrict__ gF)
{
    __shared__ __align__(16) char clds[CLDS_SZ];
    const int bi = blockIdx.x;
    const int b  = bi >> 5;
    const int rg = bi & 31;
    const int t  = threadIdx.x;

    const int lane = t & 63;
    const int ln   = lane & 31;
    const int hi   = lane >> 5;
    const int wv   = t >> 6;
    const int half = wv >> 1;
    const int pt   = wv & 1;

    {
        const float* xsrc = x + (size_t)b * C_ * HW + rg * 128;
        #pragma unroll
        for (int i = 0; i < 8; ++i) {
            const int idx = t + 256 * i;
            const int c = idx >> 5, p4 = (idx & 31) * 4;
            const float4 v = *(const float4*)(xsrc + (size_t)c * HW + p4);
            *(float4*)(clds + c * XS_ROW + p4 * 4) = v;
        }
    }

    const float* wrow0 = (ln < 8)  ? (w_theta + ln * C_)
                       : (ln < 16) ? (w_phi + (ln - 8) * C_)
                                   : (w_g + (ln - 16) * C_);
    const float* wrow1 = (ln < 16) ? (w_g + (16 + ln) * C_) : (w_g + 31 * C_);
    Frag B0[2], B1[2];
    #pragma unroll
    for (int k = 0; k < 2; ++k) {
        const float* p0 = wrow0 + 32 * half + 16 * k + 8 * hi;
        const float4 f0 = *(const float4*)(p0);
        const float4 f1 = *(const float4*)(p0 + 4);
        B0[k].u.x = cvt_pk_bf16(f0.x, f0.y); B0[k].u.y = cvt_pk_bf16(f0.z, f0.w);
        B0[k].u.z = cvt_pk_bf16(f1.x, f1.y); B0[k].u.w = cvt_pk_bf16(f1.z, f1.w);
        const float* p1 = wrow1 + 32 * half + 16 * k + 8 * hi;
        const float4 g0 = *(const float4*)(p1);
        const float4 g1 = *(const float4*)(p1 + 4);
        B1[k].u.x = cvt_pk_bf16(g0.x, g0.y); B1[k].u.y = cvt_pk_bf16(g0.z, g0.w);
        B1[k].u.z = cvt_pk_bf16(g1.x, g1.y); B1[k].u.w = cvt_pk_bf16(g1.z, g1.w);
    }
    __syncthreads();

    const int px = pt * 64 + lane;
    Frag AL[2], AH[2];
    #pragma unroll
    for (int k = 0; k < 2; ++k) {
        float v[16];
        #pragma unroll
        for (int j = 0; j < 16; ++j)
            v[j] = *(const float*)(clds + (32 * half + 16 * k + j) * XS_ROW + px * 4);
        unsigned q0 = cvt_pk_bf16(v[0],  v[1]);
        unsigned q1 = cvt_pk_bf16(v[2],  v[3]);
        unsigned q2 = cvt_pk_bf16(v[4],  v[5]);
        unsigned q3 = cvt_pk_bf16(v[6],  v[7]);
        unsigned q4 = cvt_pk_bf16(v[8],  v[9]);
        unsigned q5 = cvt_pk_bf16(v[10], v[11]);
        unsigned q6 = cvt_pk_bf16(v[12], v[13]);
        unsigned q7 = cvt_pk_bf16(v[14], v[15]);
        PLSWAP(q0, q4); PLSWAP(q1, q5); PLSWAP(q2, q6); PLSWAP(q3, q7);
        AL[k].u.x = q0; AL[k].u.y = q1; AL[k].u.z = q2; AL[k].u.w = q3;
        AH[k].u.x = q4; AH[k].u.y = q5; AH[k].u.z = q6; AH[k].u.w = q7;
    }
    __syncthreads();

    floatx16 D00 = {}, D01 = {}, D10 = {}, D11 = {};
    #pragma unroll
    for (int k = 0; k < 2; ++k) {
        D00 = __builtin_amdgcn_mfma_f32_32x32x16_bf16(AL[k].s, B0[k].s, D00, 0, 0, 0);
        D01 = __builtin_amdgcn_mfma_f32_32x32x16_bf16(AL[k].s, B1[k].s, D01, 0, 0, 0);
        D10 = __builtin_amdgcn_mfma_f32_32x32x16_bf16(AH[k].s, B0[k].s, D10, 0, 0, 0);
        D11 = __builtin_amdgcn_mfma_f32_32x32x16_bf16(AH[k].s, B1[k].s, D11, 0, 0, 0);
    }

    {
        char* base = clds + half * CV_HALF;
        #pragma unroll
        for (int r = 0; r < 16; ++r) {
            const int row = (r & 3) + 8 * (r >> 2) + 4 * hi;
            *(float*)(base + ln * CV_ROW2 + (pt * 64 + row) * 4)      = D00[r];
            *(float*)(base + ln * CV_ROW2 + (pt * 64 + 32 + row) * 4) = D10[r];
            if (ln < 16) {
                *(float*)(base + (32 + ln) * CV_ROW2 + (pt * 64 + row) * 4)      = D01[r];
                *(float*)(base + (32 + ln) * CV_ROW2 + (pt * 64 + 32 + row) * 4) = D11[r];
            }
        }
    }
    __syncthreads();

    // ---- theta: compact 8 channels, x LOG2E ----
    if (t < 128) {
        float th[8];
        #pragma unroll
        for (int oc = 0; oc < 8; ++oc)
            th[oc] = (*(const float*)(clds + oc * CV_ROW2 + t * 4)
                    + *(const float*)(clds + CV_HALF + oc * CV_ROW2 + t * 4)) * LOG2E;
        uint4 u;
        u.x = cvt_pk_bf16(th[0], th[1]); u.y = cvt_pk_bf16(th[2], th[3]);
        u.z = cvt_pk_bf16(th[4], th[5]); u.w = cvt_pk_bf16(th[6], th[7]);
        *(uint4*)(theta16 + ((size_t)b * HW + rg * 128 + t) * 8) = u;
    }

    // ---- 2x2 maxpool: phi compact [k][8]; g in fragment order ----
    for (int wi = t; wi < 1280; wi += 256) {
        const int oc = (wi >> 5) + 8;
        const int pc = wi & 31;
        const char* c0 = clds + oc * CV_ROW2;
        const char* c1 = clds + CV_HALF + oc * CV_ROW2;
        const int i0 = pc * 8;
        const float v00 = *(const float*)(c0 + i0)       + *(const float*)(c1 + i0);
        const float v01 = *(const float*)(c0 + i0 + 4)   + *(const float*)(c1 + i0 + 4);
        const float v10 = *(const float*)(c0 + i0 + 256) + *(const float*)(c1 + i0 + 256);
        const float v11 = *(const float*)(c0 + i0 + 260) + *(const float*)(c1 + i0 + 260);
        const float v = fmaxf(fmaxf(v00, v01), fmaxf(v10, v11));
        const int kg = rg * 32 + pc;
        if (oc < 16) {
            phi16[((size_t)b * KP + kg) * 8 + (oc - 8)] = __float2bfloat16(v);
        } else {
            const int c  = oc - 16;
            const int kt = kg >> 5, kk = kg & 31;
            const int s  = (kk >> 4) & 1, h2 = (kk >> 3) & 1, j = kk & 7;
            gF[((((((size_t)b * 32 + kt) * 2 + s) * 2 + h2) * 32) + c) * 8 + j]
                = __float2bfloat16(v);
        }
    }
}

// ---- attn kernel LDS (bytes), total 40960 ----
#define ATTN_ROW   136        // 34 floats: 2-way banks on epilogue reads
#define WO_OFF     34816      // 256 rows * 136
#define WO_ROW     80
#define L_OFF      (WO_OFF + 5120)
#define LDS_BYTES  (L_OFF + 1024)      // 40960

// ---------------------------------------------------------------------------
// Kernel B (v10): v9 + T14 x-residual prefetch at ENTRY. v9's single-barrier
// structure (barrier only AFTER the K-loop) means the 16 cold x loads drain
// during the first K-iter's counted vmcnt (desynchronized, compute-covered)
// instead of at a post-barrier all-waves stall. Epilogue reads no x.
// ---------------------------------------------------------------------------
__global__ __launch_bounds__(512, 4) void attn_kernel(
    const float* __restrict__ x,
    const float* __restrict__ w_o,
    const float* __restrict__ gamma_p,
    const __hip_bfloat16* __restrict__ theta16,
    const __hip_bfloat16* __restrict__ phi16,
    const __hip_bfloat16* __restrict__ gF,
    float* __restrict__ out)
{
    __shared__ __align__(16) char lds[LDS_BYTES];
    const int t = threadIdx.x;
    const int bid = (blockIdx.x & 7) * 64 + (blockIdx.x >> 3);
    const int b   = bid >> 5;
    const int qb0 = (bid & 31) * 128;

    const int lane = t & 63;
    const int wv   = t >> 6;
    const int h    = wv >> 2;          // K-half == epilogue co-half
    const int qp   = wv & 3;           // q-tile (same in loop and epilogue)
    const int hi   = lane >> 5;
    const int ln   = lane & 31;
    const int qt   = qp * 32;

    // ---- T14: issue x-residual loads FIRST (drain under the K-loop) ----
    const int eq = qb0 + qt + ln;
    const float* xres_p = x + (size_t)b * C_ * HW + eq;
    float xres[16];
    #pragma unroll
    for (int rr = 0; rr < 16; ++rr) {
        const int co = h * 32 + (rr & 3) + 8 * (rr >> 2) + 4 * hi;
        xres[rr] = xres_p[(size_t)co * HW];
    }

    // stage w_o (consumed only after the partials barrier)
    if (t < 256) {
        const int co = t >> 2, part = t & 3;
        const float4* wsrc = (const float4*)(w_o + co * 32 + part * 8);
        const float4 f0 = wsrc[0], f1 = wsrc[1];
        uint4 u;
        u.x = cvt_pk_bf16(f0.x, f0.y); u.y = cvt_pk_bf16(f0.z, f0.w);
        u.z = cvt_pk_bf16(f1.x, f1.y); u.w = cvt_pk_bf16(f1.z, f1.w);
        *(uint4*)(lds + WO_OFF + co * WO_ROW + part * 16) = u;
    }

    const uint4 z4 = {0u, 0u, 0u, 0u};
    Frag bth;
    bth.u = z4;
    if (hi == 0)
        bth.u = ((const uint4*)(theta16 + ((size_t)b * HW + qb0) * 8))[qt + ln];

    Frag ones;                          // bf16 1.0 x8 per lane: B = all-ones
    ones.u.x = 0x3F803F80u; ones.u.y = 0x3F803F80u;
    ones.u.z = 0x3F803F80u; ones.u.w = 0x3F803F80u;

    const uint4* phb = (const uint4*)(phi16 + (size_t)b * KP * 8) + h * 512;
    const uint4* gfb = (const uint4*)gF + ((size_t)b * 32 + h * 16) * 128;

    floatx16 czero = {};
    floatx16 O = {};
    floatx16 Dl = {};                   // Dl[q][*] = running l_q (all cols equal)

    #pragma unroll 2
    for (int kb = 0; kb < 16; ++kb) {
        Frag aphi, gf0, gf1;
        aphi.u = z4;
        if (hi == 0) aphi.u = phb[kb * 32 + ln];
        gf0.u = gfb[kb * 128 + lane];        // 64 consecutive uint4: coalesced
        gf1.u = gfb[kb * 128 + 64 + lane];

        floatx16 S = __builtin_amdgcn_mfma_f32_32x32x16_bf16(aphi.s, bth.s, czero, 0, 0, 0);

        float p[16];
        #pragma unroll
        for (int rr = 0; rr < 16; ++rr)
            p[rr] = __builtin_amdgcn_exp2f(S[rr]);

        Frag pa0, pa1;
        build_pfrags(p, pa0, pa1);
        O  = __builtin_amdgcn_mfma_f32_32x32x16_bf16(pa0.s, gf0.s, O, 0, 0, 0);
        O  = __builtin_amdgcn_mfma_f32_32x32x16_bf16(pa1.s, gf1.s, O, 0, 0, 0);
        Dl = __builtin_amdgcn_mfma_f32_32x32x16_bf16(pa0.s, ones.s, Dl, 0, 0, 0);
        Dl = __builtin_amdgcn_mfma_f32_32x32x16_bf16(pa1.s, ones.s, Dl, 0, 0, 0);
    }

    // write partials: rows = kh*128 + local q, cols (=ln) = g-channel
    #pragma unroll
    for (int rr = 0; rr < 16; ++rr) {
        const int rm = (rr & 3) + 8 * (rr >> 2) + 4 * hi;
        *(float*)(lds + (h * 128 + qt + rm) * ATTN_ROW + ln * 4) = O[rr];
    }
    if (ln == 0) {                      // lanes 0 (hi=0) and 32 (hi=1)
        #pragma unroll
        for (int rr = 0; rr < 16; ++rr) {
            const int rm = (rr & 3) + 8 * (rr >> 2) + 4 * hi;
            *(float*)(lds + L_OFF + (h * 128 + qt + rm) * 4) = Dl[rr];
        }
    }
    __syncthreads();

    // ---- epilogue: wave = (q-tile qp) x (co-half h); xres already in regs ----
    const float gam = gamma_p[0];
    const float lt = *(const float*)(lds + L_OFF + (qt + ln) * 4)
                   + *(const float*)(lds + L_OFF + (128 + qt + ln) * 4);
    const float gl = gam / lt;

    const char* ab0 = lds + (qt + ln) * ATTN_ROW + hi * 32;
    const char* ab1 = ab0 + 128 * ATTN_ROW;
    float4 a0 = *(const float4*)(ab0);
    float4 a1 = *(const float4*)(ab0 + 16);
    float4 a2 = *(const float4*)(ab0 + 64);
    float4 a3 = *(const float4*)(ab0 + 80);
    const float4 c0 = *(const float4*)(ab1);
    const float4 c1 = *(const float4*)(ab1 + 16);
    const float4 c2 = *(const float4*)(ab1 + 64);
    const float4 c3 = *(const float4*)(ab1 + 80);
    a0.x += c0.x; a0.y += c0.y; a0.z += c0.z; a0.w += c0.w;
    a1.x += c1.x; a1.y += c1.y; a1.z += c1.z; a1.w += c1.w;
    a2.x += c2.x; a2.y += c2.y; a2.z += c2.z; a2.w += c2.w;
    a3.x += c3.x; a3.y += c3.y; a3.z += c3.z; a3.w += c3.w;

    Frag bat0, bat1;
    bat0.u.x = cvt_pk_bf16(a0.x, a0.y); bat0.u.y = cvt_pk_bf16(a0.z, a0.w);
    bat0.u.z = cvt_pk_bf16(a1.x, a1.y); bat0.u.w = cvt_pk_bf16(a1.z, a1.w);
    bat1.u.x = cvt_pk_bf16(a2.x, a2.y); bat1.u.y = cvt_pk_bf16(a2.z, a2.w);
    bat1.u.z = cvt_pk_bf16(a3.x, a3.y); bat1.u.w = cvt_pk_bf16(a3.z, a3.w);

    const char* wb = lds + WO_OFF + (h * 32 + ln) * WO_ROW + hi * 16;
    Frag wa0, wa1;
    wa0.u = *(const uint4*)(wb);
    wa1.u = *(const uint4*)(wb + 32);

    floatx16 D = __builtin_amdgcn_mfma_f32_32x32x16_bf16(wa0.s, bat0.s, czero, 0, 0, 0);
    D = __builtin_amdgcn_mfma_f32_32x32x16_bf16(wa1.s, bat1.s, D, 0, 0, 0);

    float* ob = out + (size_t)b * C_ * HW + eq;
    #pragma unroll
    for (int rr = 0; rr < 16; ++rr) {
        const int co = h * 32 + (rr & 3) + 8 * (rr >> 2) + 4 * hi;
        ob[(size_t)co * HW] = xres[rr] + gl * D[rr];
    }
}

extern "C" void kernel_launch(void* const* d_in, const int* in_sizes, int n_in,
                              void* d_out, int out_size, void* d_ws, size_t ws_size,
                              hipStream_t stream) {
    const float* x       = (const float*)d_in[0];
    const float* w_theta = (const float*)d_in[1];
    const float* w_phi   = (const float*)d_in[2];
    const float* w_g     = (const float*)d_in[3];
    const float* w_o     = (const float*)d_in[4];
    const float* gamma   = (const float*)d_in[5];
    float* out = (float*)d_out;

    __hip_bfloat16* theta16 = (__hip_bfloat16*)d_ws;                 // 1 MB
    __hip_bfloat16* phi16   = theta16 + (size_t)B_ * HW * 8;         // 256 KB
    __hip_bfloat16* gF      = phi16   + (size_t)B_ * KP * 8;         // 1 MB

    convpool_kernel<<<dim3(B_ * 32), dim3(256), 0, stream>>>(
        x, w_theta, w_phi, w_g, theta16, phi16, gF);
    attn_kernel<<<dim3(512), dim3(512), 0, stream>>>(
        x, w_o, gamma, theta16, phi16, gF, out);
}

// Round 17
// 25.657 us; speedup vs baseline: 1.1597x; 1.1597x over previous
//
#include <hip/hip_runtime.h>
#include <hip/hip_bf16.h>

#define B_  16
#define C_  64
#define HW  4096   // 64*64
#define KP  1024   // pooled positions (32*32)
#define LOG2E 1.44269504088896f

typedef short short8 __attribute__((ext_vector_type(8)));
typedef float floatx16 __attribute__((ext_vector_type(16)));

union Frag { uint4 u; short8 s; };

__device__ __forceinline__ unsigned cvt_pk_bf16(float lo, float hi) {
    unsigned r;
    asm("v_cvt_pk_bf16_f32 %0, %1, %2" : "=v"(r) : "v"(lo), "v"(hi));
    return r;
}
#define PLSWAP(a, b) asm("v_permlane32_swap_b32 %0, %1" : "+v"(a), "+v"(b))

// Build two PV A-operand fragments (K=16 each) from 16 lane-local P values.
__device__ __forceinline__ void build_pfrags(const float* p, Frag& f0, Frag& f1) {
    unsigned u0 = cvt_pk_bf16(p[0], p[1]);
    unsigned u1 = cvt_pk_bf16(p[2], p[3]);
    unsigned u2 = cvt_pk_bf16(p[4], p[5]);
    unsigned u3 = cvt_pk_bf16(p[6], p[7]);
    PLSWAP(u0, u2);
    PLSWAP(u1, u3);
    f0.u.x = u0; f0.u.y = u1; f0.u.z = u2; f0.u.w = u3;
    unsigned v0 = cvt_pk_bf16(p[8],  p[9]);
    unsigned v1 = cvt_pk_bf16(p[10], p[11]);
    unsigned v2 = cvt_pk_bf16(p[12], p[13]);
    unsigned v3 = cvt_pk_bf16(p[14], p[15]);
    PLSWAP(v0, v2);
    PLSWAP(v1, v3);
    f1.u.x = v0; f1.u.y = v1; f1.u.z = v2; f1.u.w = v3;
}

// ---- conv kernel LDS (bytes) ----
#define XS_ROW   528          // 132 floats
#define CV_ROW2  532          // 133 floats
#define CV_HALF  25536        // 48*532
#define CLDS_SZ  51072

// ---------------------------------------------------------------------------
// Kernel A (v7): MFMA 1x1 conv (48 oc) + 2x2 pool. As v6, plus the SAME
// XCD swizzle as attn: batch b's conv blocks run on XCD b/2, so x and all
// intermediates (theta/phi/gF) are L2-resident on the XCD where attn's
// blocks for batch b will read them.
// ---------------------------------------------------------------------------
__global__ __launch_bounds__(256) void convpool_kernel(
    const float* __restrict__ x,
    const float* __restrict__ w_theta,
    const float* __restrict__ w_phi,
    const float* __restrict__ w_g,
    __hip_bfloat16* __restrict__ theta16,
    __hip_bfloat16* __restrict__ phi16,
    __hip_bfloat16* __restrict__ gF)
{
    __shared__ __align__(16) char clds[CLDS_SZ];
    const int bi = (blockIdx.x & 7) * 64 + (blockIdx.x >> 3);   // XCD-aligned
    const int b  = bi >> 5;
    const int rg = bi & 31;
    const int t  = threadIdx.x;

    const int lane = t & 63;
    const int ln   = lane & 31;
    const int hi   = lane >> 5;
    const int wv   = t >> 6;
    const int half = wv >> 1;
    const int pt   = wv & 1;

    {
        const float* xsrc = x + (size_t)b * C_ * HW + rg * 128;
        #pragma unroll
        for (int i = 0; i < 8; ++i) {
            const int idx = t + 256 * i;
            const int c = idx >> 5, p4 = (idx & 31) * 4;
            const float4 v = *(const float4*)(xsrc + (size_t)c * HW + p4);
            *(float4*)(clds + c * XS_ROW + p4 * 4) = v;
        }
    }

    const float* wrow0 = (ln < 8)  ? (w_theta + ln * C_)
                       : (ln < 16) ? (w_phi + (ln - 8) * C_)
                                   : (w_g + (ln - 16) * C_);
    const float* wrow1 = (ln < 16) ? (w_g + (16 + ln) * C_) : (w_g + 31 * C_);
    Frag B0[2], B1[2];
    #pragma unroll
    for (int k = 0; k < 2; ++k) {
        const float* p0 = wrow0 + 32 * half + 16 * k + 8 * hi;
        const float4 f0 = *(const float4*)(p0);
        const float4 f1 = *(const float4*)(p0 + 4);
        B0[k].u.x = cvt_pk_bf16(f0.x, f0.y); B0[k].u.y = cvt_pk_bf16(f0.z, f0.w);
        B0[k].u.z = cvt_pk_bf16(f1.x, f1.y); B0[k].u.w = cvt_pk_bf16(f1.z, f1.w);
        const float* p1 = wrow1 + 32 * half + 16 * k + 8 * hi;
        const float4 g0 = *(const float4*)(p1);
        const float4 g1 = *(const float4*)(p1 + 4);
        B1[k].u.x = cvt_pk_bf16(g0.x, g0.y); B1[k].u.y = cvt_pk_bf16(g0.z, g0.w);
        B1[k].u.z = cvt_pk_bf16(g1.x, g1.y); B1[k].u.w = cvt_pk_bf16(g1.z, g1.w);
    }
    __syncthreads();

    const int px = pt * 64 + lane;
    Frag AL[2], AH[2];
    #pragma unroll
    for (int k = 0; k < 2; ++k) {
        float v[16];
        #pragma unroll
        for (int j = 0; j < 16; ++j)
            v[j] = *(const float*)(clds + (32 * half + 16 * k + j) * XS_ROW + px * 4);
        unsigned q0 = cvt_pk_bf16(v[0],  v[1]);
        unsigned q1 = cvt_pk_bf16(v[2],  v[3]);
        unsigned q2 = cvt_pk_bf16(v[4],  v[5]);
        unsigned q3 = cvt_pk_bf16(v[6],  v[7]);
        unsigned q4 = cvt_pk_bf16(v[8],  v[9]);
        unsigned q5 = cvt_pk_bf16(v[10], v[11]);
        unsigned q6 = cvt_pk_bf16(v[12], v[13]);
        unsigned q7 = cvt_pk_bf16(v[14], v[15]);
        PLSWAP(q0, q4); PLSWAP(q1, q5); PLSWAP(q2, q6); PLSWAP(q3, q7);
        AL[k].u.x = q0; AL[k].u.y = q1; AL[k].u.z = q2; AL[k].u.w = q3;
        AH[k].u.x = q4; AH[k].u.y = q5; AH[k].u.z = q6; AH[k].u.w = q7;
    }
    __syncthreads();

    floatx16 D00 = {}, D01 = {}, D10 = {}, D11 = {};
    #pragma unroll
    for (int k = 0; k < 2; ++k) {
        D00 = __builtin_amdgcn_mfma_f32_32x32x16_bf16(AL[k].s, B0[k].s, D00, 0, 0, 0);
        D01 = __builtin_amdgcn_mfma_f32_32x32x16_bf16(AL[k].s, B1[k].s, D01, 0, 0, 0);
        D10 = __builtin_amdgcn_mfma_f32_32x32x16_bf16(AH[k].s, B0[k].s, D10, 0, 0, 0);
        D11 = __builtin_amdgcn_mfma_f32_32x32x16_bf16(AH[k].s, B1[k].s, D11, 0, 0, 0);
    }

    {
        char* base = clds + half * CV_HALF;
        #pragma unroll
        for (int r = 0; r < 16; ++r) {
            const int row = (r & 3) + 8 * (r >> 2) + 4 * hi;
            *(float*)(base + ln * CV_ROW2 + (pt * 64 + row) * 4)      = D00[r];
            *(float*)(base + ln * CV_ROW2 + (pt * 64 + 32 + row) * 4) = D10[r];
            if (ln < 16) {
                *(float*)(base + (32 + ln) * CV_ROW2 + (pt * 64 + row) * 4)      = D01[r];
                *(float*)(base + (32 + ln) * CV_ROW2 + (pt * 64 + 32 + row) * 4) = D11[r];
            }
        }
    }
    __syncthreads();

    // ---- theta: compact 8 channels, x LOG2E ----
    if (t < 128) {
        float th[8];
        #pragma unroll
        for (int oc = 0; oc < 8; ++oc)
            th[oc] = (*(const float*)(clds + oc * CV_ROW2 + t * 4)
                    + *(const float*)(clds + CV_HALF + oc * CV_ROW2 + t * 4)) * LOG2E;
        uint4 u;
        u.x = cvt_pk_bf16(th[0], th[1]); u.y = cvt_pk_bf16(th[2], th[3]);
        u.z = cvt_pk_bf16(th[4], th[5]); u.w = cvt_pk_bf16(th[6], th[7]);
        *(uint4*)(theta16 + ((size_t)b * HW + rg * 128 + t) * 8) = u;
    }

    // ---- 2x2 maxpool: phi compact [k][8]; g in fragment order ----
    for (int wi = t; wi < 1280; wi += 256) {
        const int oc = (wi >> 5) + 8;
        const int pc = wi & 31;
        const char* c0 = clds + oc * CV_ROW2;
        const char* c1 = clds + CV_HALF + oc * CV_ROW2;
        const int i0 = pc * 8;
        const float v00 = *(const float*)(c0 + i0)       + *(const float*)(c1 + i0);
        const float v01 = *(const float*)(c0 + i0 + 4)   + *(const float*)(c1 + i0 + 4);
        const float v10 = *(const float*)(c0 + i0 + 256) + *(const float*)(c1 + i0 + 256);
        const float v11 = *(const float*)(c0 + i0 + 260) + *(const float*)(c1 + i0 + 260);
        const float v = fmaxf(fmaxf(v00, v01), fmaxf(v10, v11));
        const int kg = rg * 32 + pc;
        if (oc < 16) {
            phi16[((size_t)b * KP + kg) * 8 + (oc - 8)] = __float2bfloat16(v);
        } else {
            const int c  = oc - 16;
            const int kt = kg >> 5, kk = kg & 31;
            const int s  = (kk >> 4) & 1, h2 = (kk >> 3) & 1, j = kk & 7;
            gF[((((((size_t)b * 32 + kt) * 2 + s) * 2 + h2) * 32) + c) * 8 + j]
                = __float2bfloat16(v);
        }
    }
}

// ---- attn kernel LDS (bytes), total 40960 ----
#define ATTN_ROW   136        // 34 floats: 2-way banks on epilogue reads
#define WO_OFF     34816      // 256 rows * 136
#define WO_ROW     80
#define L_OFF      (WO_OFF + 5120)
#define LDS_BYTES  (L_OFF + 1024)      // 40960

// ---------------------------------------------------------------------------
// Kernel B (v9, best known 28.2us total): K-loop touches no LDS; l on the
// MFMA pipe (Dl = mfma(pa, ones, Dl)); x-residual read in the epilogue
// (T14 prefetch reverted — regressed twice). Unchanged from round 15.
// ---------------------------------------------------------------------------
__global__ __launch_bounds__(512, 4) void attn_kernel(
    const float* __restrict__ x,
    const float* __restrict__ w_o,
    const float* __restrict__ gamma_p,
    const __hip_bfloat16* __restrict__ theta16,
    const __hip_bfloat16* __restrict__ phi16,
    const __hip_bfloat16* __restrict__ gF,
    float* __restrict__ out)
{
    __shared__ __align__(16) char lds[LDS_BYTES];
    const int t = threadIdx.x;
    const int bid = (blockIdx.x & 7) * 64 + (blockIdx.x >> 3);
    const int b   = bid >> 5;
    const int qb0 = (bid & 31) * 128;

    // stage w_o (consumed only after the partials barrier)
    if (t < 256) {
        const int co = t >> 2, part = t & 3;
        const float4* wsrc = (const float4*)(w_o + co * 32 + part * 8);
        const float4 f0 = wsrc[0], f1 = wsrc[1];
        uint4 u;
        u.x = cvt_pk_bf16(f0.x, f0.y); u.y = cvt_pk_bf16(f0.z, f0.w);
        u.z = cvt_pk_bf16(f1.x, f1.y); u.w = cvt_pk_bf16(f1.z, f1.w);
        *(uint4*)(lds + WO_OFF + co * WO_ROW + part * 16) = u;
    }

    const int lane = t & 63;
    const int wv   = t >> 6;
    const int h    = wv >> 2;          // K-half
    const int qp   = wv & 3;           // q-tile
    const int hi   = lane >> 5;
    const int ln   = lane & 31;
    const int qt   = qp * 32;

    const uint4 z4 = {0u, 0u, 0u, 0u};
    Frag bth;
    bth.u = z4;
    if (hi == 0)
        bth.u = ((const uint4*)(theta16 + ((size_t)b * HW + qb0) * 8))[qt + ln];

    Frag ones;                          // bf16 1.0 x8 per lane: B = all-ones
    ones.u.x = 0x3F803F80u; ones.u.y = 0x3F803F80u;
    ones.u.z = 0x3F803F80u; ones.u.w = 0x3F803F80u;

    const uint4* phb = (const uint4*)(phi16 + (size_t)b * KP * 8) + h * 512;
    const uint4* gfb = (const uint4*)gF + ((size_t)b * 32 + h * 16) * 128;

    floatx16 czero = {};
    floatx16 O = {};
    floatx16 Dl = {};                   // Dl[q][*] = running l_q (all cols equal)

    #pragma unroll 2
    for (int kb = 0; kb < 16; ++kb) {
        Frag aphi, gf0, gf1;
        aphi.u = z4;
        if (hi == 0) aphi.u = phb[kb * 32 + ln];
        gf0.u = gfb[kb * 128 + lane];        // 64 consecutive uint4: coalesced
        gf1.u = gfb[kb * 128 + 64 + lane];

        floatx16 S = __builtin_amdgcn_mfma_f32_32x32x16_bf16(aphi.s, bth.s, czero, 0, 0, 0);

        float p[16];
        #pragma unroll
        for (int rr = 0; rr < 16; ++rr)
            p[rr] = __builtin_amdgcn_exp2f(S[rr]);

        Frag pa0, pa1;
        build_pfrags(p, pa0, pa1);
        O  = __builtin_amdgcn_mfma_f32_32x32x16_bf16(pa0.s, gf0.s, O, 0, 0, 0);
        O  = __builtin_amdgcn_mfma_f32_32x32x16_bf16(pa1.s, gf1.s, O, 0, 0, 0);
        Dl = __builtin_amdgcn_mfma_f32_32x32x16_bf16(pa0.s, ones.s, Dl, 0, 0, 0);
        Dl = __builtin_amdgcn_mfma_f32_32x32x16_bf16(pa1.s, ones.s, Dl, 0, 0, 0);
    }

    // write partials: rows = kh*128 + local q, cols (=ln) = g-channel
    #pragma unroll
    for (int rr = 0; rr < 16; ++rr) {
        const int rm = (rr & 3) + 8 * (rr >> 2) + 4 * hi;
        *(float*)(lds + (h * 128 + qt + rm) * ATTN_ROW + ln * 4) = O[rr];
    }
    if (ln == 0) {                      // lanes 0 (hi=0) and 32 (hi=1)
        #pragma unroll
        for (int rr = 0; rr < 16; ++rr) {
            const int rm = (rr & 3) + 8 * (rr >> 2) + 4 * hi;
            *(float*)(lds + L_OFF + (h * 128 + qt + rm) * 4) = Dl[rr];
        }
    }
    __syncthreads();

    // ---- epilogue: wave = (q-tile wv&3) x (co-half wv>>2) ----
    const int   qtile = (wv & 3) * 32;
    const int   cot   = wv >> 2;
    const float gam = gamma_p[0];
    const float lt = *(const float*)(lds + L_OFF + (qtile + ln) * 4)
                   + *(const float*)(lds + L_OFF + (128 + qtile + ln) * 4);
    const float gl = gam / lt;

    const char* ab0 = lds + (qtile + ln) * ATTN_ROW + hi * 32;
    const char* ab1 = ab0 + 128 * ATTN_ROW;
    float4 a0 = *(const float4*)(ab0);
    float4 a1 = *(const float4*)(ab0 + 16);
    float4 a2 = *(const float4*)(ab0 + 64);
    float4 a3 = *(const float4*)(ab0 + 80);
    const float4 c0 = *(const float4*)(ab1);
    const float4 c1 = *(const float4*)(ab1 + 16);
    const float4 c2 = *(const float4*)(ab1 + 64);
    const float4 c3 = *(const float4*)(ab1 + 80);
    a0.x += c0.x; a0.y += c0.y; a0.z += c0.z; a0.w += c0.w;
    a1.x += c1.x; a1.y += c1.y; a1.z += c1.z; a1.w += c1.w;
    a2.x += c2.x; a2.y += c2.y; a2.z += c2.z; a2.w += c2.w;
    a3.x += c3.x; a3.y += c3.y; a3.z += c3.z; a3.w += c3.w;

    Frag bat0, bat1;
    bat0.u.x = cvt_pk_bf16(a0.x, a0.y); bat0.u.y = cvt_pk_bf16(a0.z, a0.w);
    bat0.u.z = cvt_pk_bf16(a1.x, a1.y); bat0.u.w = cvt_pk_bf16(a1.z, a1.w);
    bat1.u.x = cvt_pk_bf16(a2.x, a2.y); bat1.u.y = cvt_pk_bf16(a2.z, a2.w);
    bat1.u.z = cvt_pk_bf16(a3.x, a3.y); bat1.u.w = cvt_pk_bf16(a3.z, a3.w);

    const char* wb = lds + WO_OFF + (cot * 32 + ln) * WO_ROW + hi * 16;
    Frag wa0, wa1;
    wa0.u = *(const uint4*)(wb);
    wa1.u = *(const uint4*)(wb + 32);

    floatx16 D = __builtin_amdgcn_mfma_f32_32x32x16_bf16(wa0.s, bat0.s, czero, 0, 0, 0);
    D = __builtin_amdgcn_mfma_f32_32x32x16_bf16(wa1.s, bat1.s, D, 0, 0, 0);

    const int qg = qb0 + qtile + ln;
    const float* xb = x   + (size_t)b * C_ * HW + qg;
    float*       ob = out + (size_t)b * C_ * HW + qg;
    #pragma unroll
    for (int rr = 0; rr < 16; ++rr) {
        const int co = cot * 32 + (rr & 3) + 8 * (rr >> 2) + 4 * hi;
        ob[(size_t)co * HW] = xb[(size_t)co * HW] + gl * D[rr];
    }
}

extern "C" void kernel_launch(void* const* d_in, const int* in_sizes, int n_in,
                              void* d_out, int out_size, void* d_ws, size_t ws_size,
                              hipStream_t stream) {
    const float* x       = (const float*)d_in[0];
    const float* w_theta = (const float*)d_in[1];
    const float* w_phi   = (const float*)d_in[2];
    const float* w_g     = (const float*)d_in[3];
    const float* w_o     = (const float*)d_in[4];
    const float* gamma   = (const float*)d_in[5];
    float* out = (float*)d_out;

    __hip_bfloat16* theta16 = (__hip_bfloat16*)d_ws;                 // 1 MB
    __hip_bfloat16* phi16   = theta16 + (size_t)B_ * HW * 8;         // 256 KB
    __hip_bfloat16* gF      = phi16   + (size_t)B_ * KP * 8;         // 1 MB

    convpool_kernel<<<dim3(B_ * 32), dim3(256), 0, stream>>>(
        x, w_theta, w_phi, w_g, theta16, phi16, gF);
    attn_kernel<<<dim3(512), dim3(512), 0, stream>>>(
        x, w_o, gamma, theta16, phi16, gF, out);
}

// Round 19
// 25.595 us; speedup vs baseline: 1.1626x; 1.0024x over previous
//
#include <hip/hip_runtime.h>
#include <hip/hip_bf16.h>

#define B_  16
#define C_  64
#define HW  4096   // 64*64
#define KP  1024   // pooled positions (32*32)
#define LOG2E 1.44269504088896f

typedef short short8 __attribute__((ext_vector_type(8)));
typedef float floatx16 __attribute__((ext_vector_type(16)));

union Frag { uint4 u; short8 s; };

__device__ __forceinline__ unsigned cvt_pk_bf16(float lo, float hi) {
    unsigned r;
    asm("v_cvt_pk_bf16_f32 %0, %1, %2" : "=v"(r) : "v"(lo), "v"(hi));
    return r;
}
#define PLSWAP(a, b) asm("v_permlane32_swap_b32 %0, %1" : "+v"(a), "+v"(b))

// Build two PV A-operand fragments (K=16 each) from 16 lane-local P values.
__device__ __forceinline__ void build_pfrags(const float* p, Frag& f0, Frag& f1) {
    unsigned u0 = cvt_pk_bf16(p[0], p[1]);
    unsigned u1 = cvt_pk_bf16(p[2], p[3]);
    unsigned u2 = cvt_pk_bf16(p[4], p[5]);
    unsigned u3 = cvt_pk_bf16(p[6], p[7]);
    PLSWAP(u0, u2);
    PLSWAP(u1, u3);
    f0.u.x = u0; f0.u.y = u1; f0.u.z = u2; f0.u.w = u3;
    unsigned v0 = cvt_pk_bf16(p[8],  p[9]);
    unsigned v1 = cvt_pk_bf16(p[10], p[11]);
    unsigned v2 = cvt_pk_bf16(p[12], p[13]);
    unsigned v3 = cvt_pk_bf16(p[14], p[15]);
    PLSWAP(v0, v2);
    PLSWAP(v1, v3);
    f1.u.x = v0; f1.u.y = v1; f1.u.z = v2; f1.u.w = v3;
}

// ---- conv kernel LDS (bytes) ----
#define XS_ROW   528          // 132 floats
#define CV_ROW2  532          // 133 floats
#define CV_HALF  25536        // 48*532
#define CLDS_SZ  51072

// ---------------------------------------------------------------------------
// Kernel A (v7, ~5us): MFMA 1x1 conv (48 oc) + 2x2 pool, XCD-aligned with
// attn (batch b on XCD b/2): x and intermediates (theta/phi/gF) stay
// L2-resident on the XCD where attn reads them. Proven -2.5us (R17).
// ---------------------------------------------------------------------------
__global__ __launch_bounds__(256) void convpool_kernel(
    const float* __restrict__ x,
    const float* __restrict__ w_theta,
    const float* __restrict__ w_phi,
    const float* __restrict__ w_g,
    __hip_bfloat16* __restrict__ theta16,
    __hip_bfloat16* __restrict__ phi16,
    __hip_bfloat16* __restrict__ gF)
{
    __shared__ __align__(16) char clds[CLDS_SZ];
    const int bi = (blockIdx.x & 7) * 64 + (blockIdx.x >> 3);   // XCD-aligned
    const int b  = bi >> 5;
    const int rg = bi & 31;
    const int t  = threadIdx.x;

    const int lane = t & 63;
    const int ln   = lane & 31;
    const int hi   = lane >> 5;
    const int wv   = t >> 6;
    const int half = wv >> 1;
    const int pt   = wv & 1;

    {
        const float* xsrc = x + (size_t)b * C_ * HW + rg * 128;
        #pragma unroll
        for (int i = 0; i < 8; ++i) {
            const int idx = t + 256 * i;
            const int c = idx >> 5, p4 = (idx & 31) * 4;
            const float4 v = *(const float4*)(xsrc + (size_t)c * HW + p4);
            *(float4*)(clds + c * XS_ROW + p4 * 4) = v;
        }
    }

    const float* wrow0 = (ln < 8)  ? (w_theta + ln * C_)
                       : (ln < 16) ? (w_phi + (ln - 8) * C_)
                                   : (w_g + (ln - 16) * C_);
    const float* wrow1 = (ln < 16) ? (w_g + (16 + ln) * C_) : (w_g + 31 * C_);
    Frag B0[2], B1[2];
    #pragma unroll
    for (int k = 0; k < 2; ++k) {
        const float* p0 = wrow0 + 32 * half + 16 * k + 8 * hi;
        const float4 f0 = *(const float4*)(p0);
        const float4 f1 = *(const float4*)(p0 + 4);
        B0[k].u.x = cvt_pk_bf16(f0.x, f0.y); B0[k].u.y = cvt_pk_bf16(f0.z, f0.w);
        B0[k].u.z = cvt_pk_bf16(f1.x, f1.y); B0[k].u.w = cvt_pk_bf16(f1.z, f1.w);
        const float* p1 = wrow1 + 32 * half + 16 * k + 8 * hi;
        const float4 g0 = *(const float4*)(p1);
        const float4 g1 = *(const float4*)(p1 + 4);
        B1[k].u.x = cvt_pk_bf16(g0.x, g0.y); B1[k].u.y = cvt_pk_bf16(g0.z, g0.w);
        B1[k].u.z = cvt_pk_bf16(g1.x, g1.y); B1[k].u.w = cvt_pk_bf16(g1.z, g1.w);
    }
    __syncthreads();

    const int px = pt * 64 + lane;
    Frag AL[2], AH[2];
    #pragma unroll
    for (int k = 0; k < 2; ++k) {
        float v[16];
        #pragma unroll
        for (int j = 0; j < 16; ++j)
            v[j] = *(const float*)(clds + (32 * half + 16 * k + j) * XS_ROW + px * 4);
        unsigned q0 = cvt_pk_bf16(v[0],  v[1]);
        unsigned q1 = cvt_pk_bf16(v[2],  v[3]);
        unsigned q2 = cvt_pk_bf16(v[4],  v[5]);
        unsigned q3 = cvt_pk_bf16(v[6],  v[7]);
        unsigned q4 = cvt_pk_bf16(v[8],  v[9]);
        unsigned q5 = cvt_pk_bf16(v[10], v[11]);
        unsigned q6 = cvt_pk_bf16(v[12], v[13]);
        unsigned q7 = cvt_pk_bf16(v[14], v[15]);
        PLSWAP(q0, q4); PLSWAP(q1, q5); PLSWAP(q2, q6); PLSWAP(q3, q7);
        AL[k].u.x = q0; AL[k].u.y = q1; AL[k].u.z = q2; AL[k].u.w = q3;
        AH[k].u.x = q4; AH[k].u.y = q5; AH[k].u.z = q6; AH[k].u.w = q7;
    }
    __syncthreads();

    floatx16 D00 = {}, D01 = {}, D10 = {}, D11 = {};
    #pragma unroll
    for (int k = 0; k < 2; ++k) {
        D00 = __builtin_amdgcn_mfma_f32_32x32x16_bf16(AL[k].s, B0[k].s, D00, 0, 0, 0);
        D01 = __builtin_amdgcn_mfma_f32_32x32x16_bf16(AL[k].s, B1[k].s, D01, 0, 0, 0);
        D10 = __builtin_amdgcn_mfma_f32_32x32x16_bf16(AH[k].s, B0[k].s, D10, 0, 0, 0);
        D11 = __builtin_amdgcn_mfma_f32_32x32x16_bf16(AH[k].s, B1[k].s, D11, 0, 0, 0);
    }

    {
        char* base = clds + half * CV_HALF;
        #pragma unroll
        for (int r = 0; r < 16; ++r) {
            const int row = (r & 3) + 8 * (r >> 2) + 4 * hi;
            *(float*)(base + ln * CV_ROW2 + (pt * 64 + row) * 4)      = D00[r];
            *(float*)(base + ln * CV_ROW2 + (pt * 64 + 32 + row) * 4) = D10[r];
            if (ln < 16) {
                *(float*)(base + (32 + ln) * CV_ROW2 + (pt * 64 + row) * 4)      = D01[r];
                *(float*)(base + (32 + ln) * CV_ROW2 + (pt * 64 + 32 + row) * 4) = D11[r];
            }
        }
    }
    __syncthreads();

    // ---- theta: compact 8 channels, x LOG2E ----
    if (t < 128) {
        float th[8];
        #pragma unroll
        for (int oc = 0; oc < 8; ++oc)
            th[oc] = (*(const float*)(clds + oc * CV_ROW2 + t * 4)
                    + *(const float*)(clds + CV_HALF + oc * CV_ROW2 + t * 4)) * LOG2E;
        uint4 u;
        u.x = cvt_pk_bf16(th[0], th[1]); u.y = cvt_pk_bf16(th[2], th[3]);
        u.z = cvt_pk_bf16(th[4], th[5]); u.w = cvt_pk_bf16(th[6], th[7]);
        *(uint4*)(theta16 + ((size_t)b * HW + rg * 128 + t) * 8) = u;
    }

    // ---- 2x2 maxpool: phi compact [k][8]; g in fragment order ----
    for (int wi = t; wi < 1280; wi += 256) {
        const int oc = (wi >> 5) + 8;
        const int pc = wi & 31;
        const char* c0 = clds + oc * CV_ROW2;
        const char* c1 = clds + CV_HALF + oc * CV_ROW2;
        const int i0 = pc * 8;
        const float v00 = *(const float*)(c0 + i0)       + *(const float*)(c1 + i0);
        const float v01 = *(const float*)(c0 + i0 + 4)   + *(const float*)(c1 + i0 + 4);
        const float v10 = *(const float*)(c0 + i0 + 256) + *(const float*)(c1 + i0 + 256);
        const float v11 = *(const float*)(c0 + i0 + 260) + *(const float*)(c1 + i0 + 260);
        const float v = fmaxf(fmaxf(v00, v01), fmaxf(v10, v11));
        const int kg = rg * 32 + pc;
        if (oc < 16) {
            phi16[((size_t)b * KP + kg) * 8 + (oc - 8)] = __float2bfloat16(v);
        } else {
            const int c  = oc - 16;
            const int kt = kg >> 5, kk = kg & 31;
            const int s  = (kk >> 4) & 1, h2 = (kk >> 3) & 1, j = kk & 7;
            gF[((((((size_t)b * 32 + kt) * 2 + s) * 2 + h2) * 32) + c) * 8 + j]
                = __float2bfloat16(v);
        }
    }
}

// ---- attn kernel LDS (bytes), total 40960 ----
#define ATTN_ROW   136        // 34 floats: 2-way banks on epilogue reads
#define WO_OFF     34816      // 256 rows * 136
#define WO_ROW     80
#define L_OFF      (WO_OFF + 5120)
#define LDS_BYTES  (L_OFF + 1024)      // 40960

// ---------------------------------------------------------------------------
// Kernel B (v9, proven best — 25.66us total): K-loop touches no LDS
// (phi/theta/gF coalesced from XCD-local L2); l on the MFMA pipe
// (Dl = mfma(pa, ones, Dl)); launch_bounds (512,4) — the (512,8) 64-VGPR
// tier is structurally unreachable (R18: accumulator spill broke the kernel).
// ---------------------------------------------------------------------------
__global__ __launch_bounds__(512, 4) void attn_kernel(
    const float* __restrict__ x,
    const float* __restrict__ w_o,
    const float* __restrict__ gamma_p,
    const __hip_bfloat16* __restrict__ theta16,
    const __hip_bfloat16* __restrict__ phi16,
    const __hip_bfloat16* __restrict__ gF,
    float* __restrict__ out)
{
    __shared__ __align__(16) char lds[LDS_BYTES];
    const int t = threadIdx.x;
    const int bid = (blockIdx.x & 7) * 64 + (blockIdx.x >> 3);
    const int b   = bid >> 5;
    const int qb0 = (bid & 31) * 128;

    // stage w_o (consumed only after the partials barrier)
    if (t < 256) {
        const int co = t >> 2, part = t & 3;
        const float4* wsrc = (const float4*)(w_o + co * 32 + part * 8);
        const float4 f0 = wsrc[0], f1 = wsrc[1];
        uint4 u;
        u.x = cvt_pk_bf16(f0.x, f0.y); u.y = cvt_pk_bf16(f0.z, f0.w);
        u.z = cvt_pk_bf16(f1.x, f1.y); u.w = cvt_pk_bf16(f1.z, f1.w);
        *(uint4*)(lds + WO_OFF + co * WO_ROW + part * 16) = u;
    }

    const int lane = t & 63;
    const int wv   = t >> 6;
    const int h    = wv >> 2;          // K-half
    const int qp   = wv & 3;           // q-tile
    const int hi   = lane >> 5;
    const int ln   = lane & 31;
    const int qt   = qp * 32;

    const uint4 z4 = {0u, 0u, 0u, 0u};
    Frag bth;
    bth.u = z4;
    if (hi == 0)
        bth.u = ((const uint4*)(theta16 + ((size_t)b * HW + qb0) * 8))[qt + ln];

    Frag ones;                          // bf16 1.0 x8 per lane: B = all-ones
    ones.u.x = 0x3F803F80u; ones.u.y = 0x3F803F80u;
    ones.u.z = 0x3F803F80u; ones.u.w = 0x3F803F80u;

    const uint4* phb = (const uint4*)(phi16 + (size_t)b * KP * 8) + h * 512;
    const uint4* gfb = (const uint4*)gF + ((size_t)b * 32 + h * 16) * 128;

    floatx16 czero = {};
    floatx16 O = {};
    floatx16 Dl = {};                   // Dl[q][*] = running l_q (all cols equal)

    #pragma unroll 2
    for (int kb = 0; kb < 16; ++kb) {
        Frag aphi, gf0, gf1;
        aphi.u = z4;
        if (hi == 0) aphi.u = phb[kb * 32 + ln];
        gf0.u = gfb[kb * 128 + lane];        // 64 consecutive uint4: coalesced
        gf1.u = gfb[kb * 128 + 64 + lane];

        floatx16 S = __builtin_amdgcn_mfma_f32_32x32x16_bf16(aphi.s, bth.s, czero, 0, 0, 0);

        float p[16];
        #pragma unroll
        for (int rr = 0; rr < 16; ++rr)
            p[rr] = __builtin_amdgcn_exp2f(S[rr]);

        Frag pa0, pa1;
        build_pfrags(p, pa0, pa1);
        O  = __builtin_amdgcn_mfma_f32_32x32x16_bf16(pa0.s, gf0.s, O, 0, 0, 0);
        O  = __builtin_amdgcn_mfma_f32_32x32x16_bf16(pa1.s, gf1.s, O, 0, 0, 0);
        Dl = __builtin_amdgcn_mfma_f32_32x32x16_bf16(pa0.s, ones.s, Dl, 0, 0, 0);
        Dl = __builtin_amdgcn_mfma_f32_32x32x16_bf16(pa1.s, ones.s, Dl, 0, 0, 0);
    }

    // write partials: rows = kh*128 + local q, cols (=ln) = g-channel
    #pragma unroll
    for (int rr = 0; rr < 16; ++rr) {
        const int rm = (rr & 3) + 8 * (rr >> 2) + 4 * hi;
        *(float*)(lds + (h * 128 + qt + rm) * ATTN_ROW + ln * 4) = O[rr];
    }
    if (ln == 0) {                      // lanes 0 (hi=0) and 32 (hi=1)
        #pragma unroll
        for (int rr = 0; rr < 16; ++rr) {
            const int rm = (rr & 3) + 8 * (rr >> 2) + 4 * hi;
            *(float*)(lds + L_OFF + (h * 128 + qt + rm) * 4) = Dl[rr];
        }
    }
    __syncthreads();

    // ---- epilogue: wave = (q-tile wv&3) x (co-half wv>>2) ----
    const int   qtile = (wv & 3) * 32;
    const int   cot   = wv >> 2;
    const float gam = gamma_p[0];
    const float lt = *(const float*)(lds + L_OFF + (qtile + ln) * 4)
                   + *(const float*)(lds + L_OFF + (128 + qtile + ln) * 4);
    const float gl = gam / lt;

    const char* ab0 = lds + (qtile + ln) * ATTN_ROW + hi * 32;
    const char* ab1 = ab0 + 128 * ATTN_ROW;
    float4 a0 = *(const float4*)(ab0);
    float4 a1 = *(const float4*)(ab0 + 16);
    float4 a2 = *(const float4*)(ab0 + 64);
    float4 a3 = *(const float4*)(ab0 + 80);
    const float4 c0 = *(const float4*)(ab1);
    const float4 c1 = *(const float4*)(ab1 + 16);
    const float4 c2 = *(const float4*)(ab1 + 64);
    const float4 c3 = *(const float4*)(ab1 + 80);
    a0.x += c0.x; a0.y += c0.y; a0.z += c0.z; a0.w += c0.w;
    a1.x += c1.x; a1.y += c1.y; a1.z += c1.z; a1.w += c1.w;
    a2.x += c2.x; a2.y += c2.y; a2.z += c2.z; a2.w += c2.w;
    a3.x += c3.x; a3.y += c3.y; a3.z += c3.z; a3.w += c3.w;

    Frag bat0, bat1;
    bat0.u.x = cvt_pk_bf16(a0.x, a0.y); bat0.u.y = cvt_pk_bf16(a0.z, a0.w);
    bat0.u.z = cvt_pk_bf16(a1.x, a1.y); bat0.u.w = cvt_pk_bf16(a1.z, a1.w);
    bat1.u.x = cvt_pk_bf16(a2.x, a2.y); bat1.u.y = cvt_pk_bf16(a2.z, a2.w);
    bat1.u.z = cvt_pk_bf16(a3.x, a3.y); bat1.u.w = cvt_pk_bf16(a3.z, a3.w);

    const char* wb = lds + WO_OFF + (cot * 32 + ln) * WO_ROW + hi * 16;
    Frag wa0, wa1;
    wa0.u = *(const uint4*)(wb);
    wa1.u = *(const uint4*)(wb + 32);

    floatx16 D = __builtin_amdgcn_mfma_f32_32x32x16_bf16(wa0.s, bat0.s, czero, 0, 0, 0);
    D = __builtin_amdgcn_mfma_f32_32x32x16_bf16(wa1.s, bat1.s, D, 0, 0, 0);

    const int qg = qb0 + qtile + ln;
    const float* xb = x   + (size_t)b * C_ * HW + qg;
    float*       ob = out + (size_t)b * C_ * HW + qg;
    #pragma unroll
    for (int rr = 0; rr < 16; ++rr) {
        const int co = cot * 32 + (rr & 3) + 8 * (rr >> 2) + 4 * hi;
        ob[(size_t)co * HW] = xb[(size_t)co * HW] + gl * D[rr];
    }
}

extern "C" void kernel_launch(void* const* d_in, const int* in_sizes, int n_in,
                              void* d_out, int out_size, void* d_ws, size_t ws_size,
                              hipStream_t stream) {
    const float* x       = (const float*)d_in[0];
    const float* w_theta = (const float*)d_in[1];
    const float* w_phi   = (const float*)d_in[2];
    const float* w_g     = (const float*)d_in[3];
    const float* w_o     = (const float*)d_in[4];
    const float* gamma   = (const float*)d_in[5];
    float* out = (float*)d_out;

    __hip_bfloat16* theta16 = (__hip_bfloat16*)d_ws;                 // 1 MB
    __hip_bfloat16* phi16   = theta16 + (size_t)B_ * HW * 8;         // 256 KB
    __hip_bfloat16* gF      = phi16   + (size_t)B_ * KP * 8;         // 1 MB

    convpool_kernel<<<dim3(B_ * 32), dim3(256), 0, stream>>>(
        x, w_theta, w_phi, w_g, theta16, phi16, gF);
    attn_kernel<<<dim3(512), dim3(512), 0, stream>>>(
        x, w_o, gamma, theta16, phi16, gF, out);
}